// Round 7
// baseline (522.719 us; speedup 1.0000x reference)
//
#include <hip/hip_runtime.h>

// Problem constants
#define B_   4
#define C_   256
#define N_   4096   // H*W
#define D_   32     // qk projection dim
#define CP   264    // proj s_x row stride (halves): 256 + 8
#define L2E  1.44269504f

typedef _Float16 half8  __attribute__((ext_vector_type(8)));
typedef _Float16 half4v __attribute__((ext_vector_type(4)));
typedef _Float16 half2v __attribute__((ext_vector_type(2)));
typedef __fp16   fp16x2 __attribute__((ext_vector_type(2)));
typedef float    f32x4  __attribute__((ext_vector_type(4)));

union PBU { half2v h2[4]; half8 h8; };

static __device__ inline half2v pk2(float a, float b) {
    union { fp16x2 f; half2v h; } u;
    u.f = __builtin_amdgcn_cvt_pkrtz(a, b);
    return u.h;
}

// ---------------------------------------------------------------------------
// Kernel 0: convert W (f32) -> Wh (f16), A-frag layout:
// Wh[((t*8+kc)*16 + row)*32 + kk] = W_t[row][kc*32+kk], t: 0-1 q, 2-3 k, 4-19 v
// ---------------------------------------------------------------------------
__global__ __launch_bounds__(256) void wcvt_kernel(
    const float* __restrict__ Wq, const float* __restrict__ Wk,
    const float* __restrict__ Wv, _Float16* __restrict__ Wh)
{
    const int idx = blockIdx.x * 256 + threadIdx.x;
    const int kk  = idx & 31;
    const int row = (idx >> 5) & 15;
    const int kc  = (idx >> 9) & 7;
    const int t   = idx >> 12;
    const int c   = kc*32 + kk;
    float v;
    if (t < 2)      v = Wq[(t*16 + row)*C_ + c];
    else if (t < 4) v = Wk[((t-2)*16 + row)*C_ + c];
    else            v = Wv[((t-4)*16 + row)*C_ + c];
    Wh[idx] = (_Float16)v;
}

// ---------------------------------------------------------------------------
// Kernel 1: projections. Single-barrier full-tile staging (R5 structure).
// V output: K=32-A-frag layout with PERMUTED j so flash's P B-frag needs no
// shuffle:  frag(jc32, ctg) is 512 contiguous halves;
//   element (c_local, j_local32):  t=j_local>>4, mm=j_local&15,
//   lane' = 16*(mm>>2) + c_local, e = 4*t + (mm&3).
// V frags staged through LDS (reuse s_s) -> coalesced dwordx4 stores.
// Qh,Kh stay (B, 4 dchunk, N, 8) f16.
// ---------------------------------------------------------------------------
__global__ __launch_bounds__(256, 2) void proj_kernel(
    const float* __restrict__ sem, const float* __restrict__ str,
    const _Float16* __restrict__ Wh,
    const float* __restrict__ bq, const float* __restrict__ bk,
    const float* __restrict__ bv,
    _Float16* __restrict__ Qh, _Float16* __restrict__ Kh, _Float16* __restrict__ Vh2)
{
    __shared__ __align__(16) _Float16 s_x[64 * CP];   // structural, 33 KB
    __shared__ __align__(16) _Float16 s_s[64 * CP];   // semantic (h==0); V-frag image later

    const int bid = blockIdx.x;
    const int h   = bid & 1;
    const int nt6 = (bid >> 1) & 63;
    const int b   = bid >> 7;
    const int n0  = nt6 * 64;
    const int tid = threadIdx.x;
    const int w    = tid >> 6;
    const int lane = tid & 63;
    const int quad = lane >> 4;
    const int l15  = lane & 15;

    const int cnt = (w < 2) ? 3 : 2;
    const int t0  = h*10 + ((w < 2) ? w*3 : 6 + (w-2)*2);
    const bool need_sem = (h == 0);

    f32x4 acc[3][4];
    #pragma unroll
    for (int i = 0; i < 3; ++i)
        #pragma unroll
        for (int j = 0; j < 4; ++j) { acc[i][j][0]=0.f; acc[i][j][1]=0.f; acc[i][j][2]=0.f; acc[i][j][3]=0.f; }

    const size_t xbase = (size_t)b * C_ * N_;

    // ---- stage the whole 64n x 256c tile, then ONE barrier ----
    #pragma unroll
    for (int r = 0; r < 8; ++r) {
        const int slot = r*256 + tid;
        const int nq = slot & 15;        // n-quad
        const int cp = slot >> 4;        // c-pair 0..127
        const float* p0 = str + xbase + (size_t)(2*cp) * N_ + n0 + nq*4;
        const float4 a4 = *(const float4*)p0;
        const float4 b4 = *(const float4*)(p0 + N_);
        #pragma unroll
        for (int t = 0; t < 4; ++t) {
            half2v hp; hp[0] = (_Float16)a4[t]; hp[1] = (_Float16)b4[t];
            *(half2v*)(s_x + (nq*4 + t)*CP + 2*cp) = hp;
        }
        if (need_sem) {
            const float* p1 = sem + xbase + (size_t)(2*cp) * N_ + n0 + nq*4;
            const float4 c4 = *(const float4*)p1;
            const float4 d4 = *(const float4*)(p1 + N_);
            #pragma unroll
            for (int t = 0; t < 4; ++t) {
                half2v hp; hp[0] = (_Float16)c4[t]; hp[1] = (_Float16)d4[t];
                *(half2v*)(s_s + (nq*4 + t)*CP + 2*cp) = hp;
            }
        }
    }
    __syncthreads();

    // ---- compute ----
    #pragma unroll 1
    for (int kc = 0; kc < 8; ++kc) {
        half8 bfr[4], sfr[4];
        #pragma unroll
        for (int nt = 0; nt < 4; ++nt)
            bfr[nt] = *(const half8*)(s_x + (nt*16 + l15)*CP + kc*32 + quad*8);
        if (w == 0 && need_sem) {
            #pragma unroll
            for (int nt = 0; nt < 4; ++nt)
                sfr[nt] = *(const half8*)(s_s + (nt*16 + l15)*CP + kc*32 + quad*8);
        }
        #pragma unroll
        for (int mi = 0; mi < 3; ++mi) {
            if (mi >= cnt) break;
            const int t = t0 + mi;
            half8 af = *(const half8*)(Wh + ((size_t)((t*8 + kc)*16 + l15))*32 + quad*8);
            #pragma unroll
            for (int nt = 0; nt < 4; ++nt)
                acc[mi][nt] = __builtin_amdgcn_mfma_f32_16x16x32_f16(
                                  af, (t < 2) ? sfr[nt] : bfr[nt], acc[mi][nt], 0, 0, 0);
        }
    }

    __syncthreads();   // s_s free -> reuse as V-frag image

    // ---- epilogue ----
    const int ctg0 = h ? 6 : 0;
    #pragma unroll
    for (int mi = 0; mi < 3; ++mi) {
        if (mi >= cnt) break;
        const int t = t0 + mi;
        if (t < 4) {
            const bool isq = (t < 2);
            const int  tt  = isq ? t : (t - 2);
            f32x4 b4 = *(const f32x4*)((isq ? bq : bk) + tt*16 + quad*4);
            _Float16* dst = isq ? Qh : Kh;
            const int dc  = tt*2 + (quad >> 1);
            const int off = (quad & 1) * 4;
            #pragma unroll
            for (int nt = 0; nt < 4; ++nt) {
                const int n = n0 + nt*16 + l15;
                f32x4 a = acc[mi][nt];
                half4v hq;
                hq[0]=(_Float16)(a[0]+b4[0]); hq[1]=(_Float16)(a[1]+b4[1]);
                hq[2]=(_Float16)(a[2]+b4[2]); hq[3]=(_Float16)(a[3]+b4[3]);
                *(half4v*)(dst + ((size_t)(b*4 + dc) * N_ + n) * 8 + off) = hq;
            }
        } else {
            const int ctg = t - 4;
            const int vt  = ctg - ctg0;
            f32x4 b4 = *(const f32x4*)(bv + ctg*16 + quad*4);
            // write to LDS frag image: frag_local = vt*2 + (nt>>1)
            const int lanep = 16*(l15 >> 2) + quad*4;         // + r
            const int ebase = (l15 & 3);                       // e = 4*(nt&1) + (l15&3)
            #pragma unroll
            for (int nt = 0; nt < 4; ++nt) {
                const int fl = vt*2 + (nt >> 1);
                const int e  = 4*(nt & 1) + ebase;
                f32x4 a = acc[mi][nt];
                #pragma unroll
                for (int r = 0; r < 4; ++r)
                    s_s[fl*512 + (lanep + r)*8 + e] = (_Float16)(a[r] + b4[r]);
            }
        }
    }
    __syncthreads();

    // ---- stream V-frag image to global, coalesced dwordx4 ----
    const int nfrag = h ? 20 : 12;
    _Float16* vb = Vh2 + (size_t)b * (size_t)N_ * C_;
    for (int idx = tid; idx < nfrag*64; idx += 256) {
        const int fl = idx >> 6;
        const int el = idx & 63;
        const int vt = fl >> 1;
        const int g  = fl & 1;
        const int gf = ((n0 >> 5) + g)*16 + ctg0 + vt;
        *(uint4*)(vb + (size_t)gf*512 + el*8) = *(const uint4*)(s_s + fl*512 + el*8);
    }
}

// ---------------------------------------------------------------------------
// Kernel 2: flash attention v6 — PV on 16x16x32 via permuted-j (P straight
// from registers), exp2-fma softmax with fixed per-j-half max, j-split x2.
// Block = 512 thr = 8 waves: wave = (c-slice cw 0..3, j-half jh 0..1), each
// wave = 32 i-rows x 64 c x 2048 j. Phase 0: 8-way j-split exact max, one
// barrier. Main loop barrier-free, K/V double-buffered in regs. End: j-half
// O/l/m merge through LDS, fused gamma*O/l + semantic store.
// ---------------------------------------------------------------------------
__global__ __launch_bounds__(512, 4) void flash_kernel(
    const _Float16* __restrict__ Qh, const _Float16* __restrict__ Kh,
    const _Float16* __restrict__ Vh2, const float* __restrict__ sem,
    const float* __restrict__ gma, float* __restrict__ out)
{
    __shared__ float s_o[4 * 32 * 64];   // 32 KB: [cw][reg 0..31][lane]
    __shared__ float s_mp[8*32];
    __shared__ float s_m2[4*32];
    __shared__ float s_l2[4*32];

    const int bid = blockIdx.x;          // 512 blocks
    const int b   = bid >> 7;
    const int i0  = (bid & 127) * 32;
    const int tid = threadIdx.x;
    const int w    = tid >> 6;           // 0..7
    const int lane = tid & 63;
    const int quad = lane >> 4;
    const int l15  = lane & 15;
    const int cw   = w & 3;
    const int jh   = w >> 2;
    const int cw4  = cw * 4;
    const int jbase = jh * 2048;
    const int jend  = jbase + 2048;

    // Q B-frags: B[k=d][n=i], d-chunk = quad
    const _Float16* qbase = Qh + (size_t)(b*4 + quad) * N_ * 8;
    const half8 qf0 = *(const half8*)(qbase + (size_t)(i0 + l15) * 8);
    const half8 qf1 = *(const half8*)(qbase + (size_t)(i0 + 16 + l15) * 8);
    const _Float16* klane = Kh + ((size_t)(b*4 + quad) * N_ + l15) * 8;
    const _Float16* vbase = Vh2 + (size_t)b * (size_t)N_ * C_ + lane*8;

    // ---- phase 0: exact row max, 8-way j-split ----
    float mx0 = -3e38f, mx1 = -3e38f;
    #pragma unroll 1
    for (int it = 0; it < 8; ++it) {
        const int jj = w*512 + it*64;
        #pragma unroll
        for (int js = 0; js < 4; ++js) {
            half8 kf = *(const half8*)(klane + (size_t)(jj + js*16) * 8);
            f32x4 z; z[0]=0.f; z[1]=0.f; z[2]=0.f; z[3]=0.f;
            f32x4 s0 = __builtin_amdgcn_mfma_f32_16x16x32_f16(kf, qf0, z, 0, 0, 0);
            f32x4 s1 = __builtin_amdgcn_mfma_f32_16x16x32_f16(kf, qf1, z, 0, 0, 0);
            #pragma unroll
            for (int r = 0; r < 4; ++r) { mx0 = fmaxf(mx0, s0[r]); mx1 = fmaxf(mx1, s1[r]); }
        }
    }
    mx0 = fmaxf(mx0, __shfl_xor(mx0, 16)); mx0 = fmaxf(mx0, __shfl_xor(mx0, 32));
    mx1 = fmaxf(mx1, __shfl_xor(mx1, 16)); mx1 = fmaxf(mx1, __shfl_xor(mx1, 32));
    if (lane < 32) s_mp[w*32 + lane] = (lane < 16) ? mx0 : mx1;
    __syncthreads();
    float mf0 = -3e38f, mf1 = -3e38f;
    #pragma unroll
    for (int ww = 0; ww < 4; ++ww) {        // combine the 4 chunks of MY j-half
        const int wi = jh*4 + ww;
        mf0 = fmaxf(mf0, s_mp[wi*32 + l15]);
        mf1 = fmaxf(mf1, s_mp[wi*32 + 16 + l15]);
    }
    const float mc0 = mf0 * L2E, mc1 = mf1 * L2E;

    // ---- main loop ----
    f32x4 acc[4][2];
    #pragma unroll
    for (int ct = 0; ct < 4; ++ct)
        #pragma unroll
        for (int f = 0; f < 2; ++f) { acc[ct][f][0]=0.f; acc[ct][f][1]=0.f; acc[ct][f][2]=0.f; acc[ct][f][3]=0.f; }
    float l0 = 0.f, l1 = 0.f;

    half8 ka[4], kb[4], va[2][4], vb[2][4];

    auto pref = [&](half8 (&kf)[4], half8 (&vf)[2][4], int j0) {
        #pragma unroll
        for (int js = 0; js < 4; ++js)
            kf[js] = *(const half8*)(klane + (size_t)(j0 + js*16) * 8);
        const int jc0 = j0 >> 5;
        #pragma unroll
        for (int g = 0; g < 2; ++g)
            #pragma unroll
            for (int ct = 0; ct < 4; ++ct)
                vf[g][ct] = *(const half8*)(vbase + (size_t)((jc0 + g)*16 + cw4 + ct) * 512);
    };

    auto step = [&](const half8 (&kf)[4], const half8 (&vf)[2][4],
                    half8 (&kfn)[4], half8 (&vfn)[2][4], int jnext) {
        f32x4 z; z[0]=0.f; z[1]=0.f; z[2]=0.f; z[3]=0.f;
        f32x4 sf0[4], sf1[4];
        #pragma unroll
        for (int js = 0; js < 4; ++js) {
            sf0[js] = __builtin_amdgcn_mfma_f32_16x16x32_f16(kf[js], qf0, z, 0, 0, 0);
            sf1[js] = __builtin_amdgcn_mfma_f32_16x16x32_f16(kf[js], qf1, z, 0, 0, 0);
        }
        if (jnext < jend) pref(kfn, vfn, jnext);

        #pragma unroll
        for (int g = 0; g < 2; ++g) {
            PBU p0, p1;
            #pragma unroll
            for (int tt = 0; tt < 2; ++tt) {
                const int js = 2*g + tt;
                float a0 = exp2f(fmaf(sf0[js][0], L2E, -mc0));
                float a1 = exp2f(fmaf(sf0[js][1], L2E, -mc0));
                float a2 = exp2f(fmaf(sf0[js][2], L2E, -mc0));
                float a3 = exp2f(fmaf(sf0[js][3], L2E, -mc0));
                l0 += (a0+a1)+(a2+a3);
                p0.h2[tt*2+0] = pk2(a0, a1); p0.h2[tt*2+1] = pk2(a2, a3);
                float b0 = exp2f(fmaf(sf1[js][0], L2E, -mc1));
                float b1 = exp2f(fmaf(sf1[js][1], L2E, -mc1));
                float b2 = exp2f(fmaf(sf1[js][2], L2E, -mc1));
                float b3 = exp2f(fmaf(sf1[js][3], L2E, -mc1));
                l1 += (b0+b1)+(b2+b3);
                p1.h2[tt*2+0] = pk2(b0, b1); p1.h2[tt*2+1] = pk2(b2, b3);
            }
            #pragma unroll
            for (int ct = 0; ct < 4; ++ct) {
                acc[ct][0] = __builtin_amdgcn_mfma_f32_16x16x32_f16(vf[g][ct], p0.h8, acc[ct][0], 0, 0, 0);
                acc[ct][1] = __builtin_amdgcn_mfma_f32_16x16x32_f16(vf[g][ct], p1.h8, acc[ct][1], 0, 0, 0);
            }
        }
    };

    pref(ka, va, jbase);
    #pragma unroll 1
    for (int s = 0; s < 16; ++s) {
        const int j0 = jbase + s*128;
        step(ka, va, kb, vb, j0 + 64);
        step(kb, vb, ka, va, j0 + 128);
    }

    // ---- l across quads (disjoint j per quad) ----
    l0 += __shfl_xor(l0, 16); l0 += __shfl_xor(l0, 32);
    l1 += __shfl_xor(l1, 16); l1 += __shfl_xor(l1, 32);

    // ---- merge j-halves through LDS, fused epilogue ----
    __syncthreads();
    if (jh == 1) {
        #pragma unroll
        for (int ct = 0; ct < 4; ++ct)
            #pragma unroll
            for (int e = 0; e < 4; ++e) {
                s_o[(cw*32 + ct*8 + e)*64 + lane]     = acc[ct][0][e];
                s_o[(cw*32 + ct*8 + 4 + e)*64 + lane] = acc[ct][1][e];
            }
        if (quad == 0) {
            s_m2[cw*32 + l15]      = mf0;  s_m2[cw*32 + 16 + l15] = mf1;
            s_l2[cw*32 + l15]      = l0;   s_l2[cw*32 + 16 + l15] = l1;
        }
    }
    __syncthreads();
    if (jh == 0) {
        const float md0 = s_m2[cw*32 + l15],      md1 = s_m2[cw*32 + 16 + l15];
        const float ld0 = s_l2[cw*32 + l15],      ld1 = s_l2[cw*32 + 16 + l15];
        const float g   = gma[0];
        const float mm0 = fmaxf(mf0, md0), mm1 = fmaxf(mf1, md1);
        const float as0 = exp2f((mf0 - mm0)*L2E), ad0 = exp2f((md0 - mm0)*L2E);
        const float as1 = exp2f((mf1 - mm1)*L2E), ad1 = exp2f((md1 - mm1)*L2E);
        const float ln0 = l0*as0 + ld0*ad0, ln1 = l1*as1 + ld1*ad1;
        const float ca0 = as0*g/ln0, cd0 = ad0*g/ln0;
        const float ca1 = as1*g/ln1, cd1 = ad1*g/ln1;
        #pragma unroll
        for (int ct = 0; ct < 4; ++ct)
            #pragma unroll
            for (int e = 0; e < 4; ++e) {
                const float od0 = s_o[(cw*32 + ct*8 + e)*64 + lane];
                const float od1 = s_o[(cw*32 + ct*8 + 4 + e)*64 + lane];
                const int c = cw*64 + ct*16 + quad*4 + e;
                const size_t idx0 = ((size_t)(b*C_ + c)) * N_ + i0 + l15;
                out[idx0]      = acc[ct][0][e]*ca0 + od0*cd0 + sem[idx0];
                out[idx0 + 16] = acc[ct][1][e]*ca1 + od1*cd1 + sem[idx0 + 16];
            }
    }
}

extern "C" void kernel_launch(void* const* d_in, const int* in_sizes, int n_in,
                              void* d_out, int out_size, void* d_ws, size_t ws_size,
                              hipStream_t stream) {
    const float* sem = (const float*)d_in[0];
    const float* str = (const float*)d_in[1];
    const float* Wq  = (const float*)d_in[2];
    const float* bq  = (const float*)d_in[3];
    const float* Wk  = (const float*)d_in[4];
    const float* bk  = (const float*)d_in[5];
    const float* Wv  = (const float*)d_in[6];
    const float* bv  = (const float*)d_in[7];
    const float* gma = (const float*)d_in[8];
    float* out = (float*)d_out;

    // Workspace (f16): Qh 1MB | Kh 1MB | Vh2 8MB | Wh 160KB
    _Float16* Qh  = (_Float16*)d_ws;
    _Float16* Kh  = Qh + (size_t)B_*N_*D_;
    _Float16* Vh2 = Kh + (size_t)B_*N_*D_;
    _Float16* Wh  = Vh2 + (size_t)B_*C_*N_;

    hipLaunchKernelGGL(wcvt_kernel, dim3(320), dim3(256), 0, stream, Wq, Wk, Wv, Wh);
    hipLaunchKernelGGL(proj_kernel, dim3(B_*(N_/64)*2), dim3(256), 0, stream,
                       sem, str, Wh, bq, bk, bv, Qh, Kh, Vh2);
    hipLaunchKernelGGL(flash_kernel, dim3(B_*(N_/32)), dim3(512), 0, stream,
                       Qh, Kh, Vh2, sem, gma, out);
}

// Round 8
// 208.058 us; speedup vs baseline: 2.5124x; 2.5124x over previous
//
#include <hip/hip_runtime.h>

// Problem constants
#define B_   4
#define C_   256
#define N_   4096   // H*W
#define D_   32     // qk projection dim
#define CP   264    // proj s_x row stride (halves): 256 + 8
#define L2E  1.44269504f

typedef _Float16 half8  __attribute__((ext_vector_type(8)));
typedef _Float16 half4v __attribute__((ext_vector_type(4)));
typedef _Float16 half2v __attribute__((ext_vector_type(2)));
typedef __fp16   fp16x2 __attribute__((ext_vector_type(2)));
typedef float    f32x4  __attribute__((ext_vector_type(4)));

union PBU { half2v h2[4]; half8 h8; };

static __device__ inline half2v pk2(float a, float b) {
    union { fp16x2 f; half2v h; } u;
    u.f = __builtin_amdgcn_cvt_pkrtz(a, b);
    return u.h;
}

// ---------------------------------------------------------------------------
// Kernel 0: convert W (f32) -> Wh (f16), A-frag layout:
// Wh[((t*8+kc)*16 + row)*32 + kk] = W_t[row][kc*32+kk], t: 0-1 q, 2-3 k, 4-19 v
// ---------------------------------------------------------------------------
__global__ __launch_bounds__(256) void wcvt_kernel(
    const float* __restrict__ Wq, const float* __restrict__ Wk,
    const float* __restrict__ Wv, _Float16* __restrict__ Wh)
{
    const int idx = blockIdx.x * 256 + threadIdx.x;
    const int kk  = idx & 31;
    const int row = (idx >> 5) & 15;
    const int kc  = (idx >> 9) & 7;
    const int t   = idx >> 12;
    const int c   = kc*32 + kk;
    float v;
    if (t < 2)      v = Wq[(t*16 + row)*C_ + c];
    else if (t < 4) v = Wk[((t-2)*16 + row)*C_ + c];
    else            v = Wv[((t-4)*16 + row)*C_ + c];
    Wh[idx] = (_Float16)v;
}

// ---------------------------------------------------------------------------
// Kernel 1: projections. Single-barrier full-tile staging.
// V output: K=32-A-frag layout with PERMUTED j so flash's P B-frag needs no
// shuffle. V frags staged through LDS (reuse s_s) -> coalesced dwordx4 stores.
// Qh,Kh stay (B, 4 dchunk, N, 8) f16.
// ---------------------------------------------------------------------------
__global__ __launch_bounds__(256, 2) void proj_kernel(
    const float* __restrict__ sem, const float* __restrict__ str,
    const _Float16* __restrict__ Wh,
    const float* __restrict__ bq, const float* __restrict__ bk,
    const float* __restrict__ bv,
    _Float16* __restrict__ Qh, _Float16* __restrict__ Kh, _Float16* __restrict__ Vh2)
{
    __shared__ __align__(16) _Float16 s_x[64 * CP];   // structural, 33 KB
    __shared__ __align__(16) _Float16 s_s[64 * CP];   // semantic (h==0); V-frag image later

    const int bid = blockIdx.x;
    const int h   = bid & 1;
    const int nt6 = (bid >> 1) & 63;
    const int b   = bid >> 7;
    const int n0  = nt6 * 64;
    const int tid = threadIdx.x;
    const int w    = tid >> 6;
    const int lane = tid & 63;
    const int quad = lane >> 4;
    const int l15  = lane & 15;

    const int cnt = (w < 2) ? 3 : 2;
    const int t0  = h*10 + ((w < 2) ? w*3 : 6 + (w-2)*2);
    const bool need_sem = (h == 0);

    f32x4 acc[3][4];
    #pragma unroll
    for (int i = 0; i < 3; ++i)
        #pragma unroll
        for (int j = 0; j < 4; ++j) { acc[i][j][0]=0.f; acc[i][j][1]=0.f; acc[i][j][2]=0.f; acc[i][j][3]=0.f; }

    const size_t xbase = (size_t)b * C_ * N_;

    // ---- stage the whole 64n x 256c tile, then ONE barrier ----
    #pragma unroll
    for (int r = 0; r < 8; ++r) {
        const int slot = r*256 + tid;
        const int nq = slot & 15;        // n-quad
        const int cp = slot >> 4;        // c-pair 0..127
        const float* p0 = str + xbase + (size_t)(2*cp) * N_ + n0 + nq*4;
        const float4 a4 = *(const float4*)p0;
        const float4 b4 = *(const float4*)(p0 + N_);
        #pragma unroll
        for (int t = 0; t < 4; ++t) {
            half2v hp; hp[0] = (_Float16)a4[t]; hp[1] = (_Float16)b4[t];
            *(half2v*)(s_x + (nq*4 + t)*CP + 2*cp) = hp;
        }
        if (need_sem) {
            const float* p1 = sem + xbase + (size_t)(2*cp) * N_ + n0 + nq*4;
            const float4 c4 = *(const float4*)p1;
            const float4 d4 = *(const float4*)(p1 + N_);
            #pragma unroll
            for (int t = 0; t < 4; ++t) {
                half2v hp; hp[0] = (_Float16)c4[t]; hp[1] = (_Float16)d4[t];
                *(half2v*)(s_s + (nq*4 + t)*CP + 2*cp) = hp;
            }
        }
    }
    __syncthreads();

    // ---- compute ----
    #pragma unroll 1
    for (int kc = 0; kc < 8; ++kc) {
        half8 bfr[4], sfr[4];
        #pragma unroll
        for (int nt = 0; nt < 4; ++nt)
            bfr[nt] = *(const half8*)(s_x + (nt*16 + l15)*CP + kc*32 + quad*8);
        if (w == 0 && need_sem) {
            #pragma unroll
            for (int nt = 0; nt < 4; ++nt)
                sfr[nt] = *(const half8*)(s_s + (nt*16 + l15)*CP + kc*32 + quad*8);
        }
        #pragma unroll
        for (int mi = 0; mi < 3; ++mi) {
            if (mi >= cnt) break;
            const int t = t0 + mi;
            half8 af = *(const half8*)(Wh + ((size_t)((t*8 + kc)*16 + l15))*32 + quad*8);
            #pragma unroll
            for (int nt = 0; nt < 4; ++nt)
                acc[mi][nt] = __builtin_amdgcn_mfma_f32_16x16x32_f16(
                                  af, (t < 2) ? sfr[nt] : bfr[nt], acc[mi][nt], 0, 0, 0);
        }
    }

    __syncthreads();   // s_s free -> reuse as V-frag image

    // ---- epilogue ----
    const int ctg0 = h ? 6 : 0;
    #pragma unroll
    for (int mi = 0; mi < 3; ++mi) {
        if (mi >= cnt) break;
        const int t = t0 + mi;
        if (t < 4) {
            const bool isq = (t < 2);
            const int  tt  = isq ? t : (t - 2);
            f32x4 b4 = *(const f32x4*)((isq ? bq : bk) + tt*16 + quad*4);
            _Float16* dst = isq ? Qh : Kh;
            const int dc  = tt*2 + (quad >> 1);
            const int off = (quad & 1) * 4;
            #pragma unroll
            for (int nt = 0; nt < 4; ++nt) {
                const int n = n0 + nt*16 + l15;
                f32x4 a = acc[mi][nt];
                half4v hq;
                hq[0]=(_Float16)(a[0]+b4[0]); hq[1]=(_Float16)(a[1]+b4[1]);
                hq[2]=(_Float16)(a[2]+b4[2]); hq[3]=(_Float16)(a[3]+b4[3]);
                *(half4v*)(dst + ((size_t)(b*4 + dc) * N_ + n) * 8 + off) = hq;
            }
        } else {
            const int ctg = t - 4;
            const int vt  = ctg - ctg0;
            f32x4 b4 = *(const f32x4*)(bv + ctg*16 + quad*4);
            const int lanep = 16*(l15 >> 2) + quad*4;         // + r
            const int ebase = (l15 & 3);                       // e = 4*(nt&1) + (l15&3)
            #pragma unroll
            for (int nt = 0; nt < 4; ++nt) {
                const int fl = vt*2 + (nt >> 1);
                const int e  = 4*(nt & 1) + ebase;
                f32x4 a = acc[mi][nt];
                #pragma unroll
                for (int r = 0; r < 4; ++r)
                    s_s[fl*512 + (lanep + r)*8 + e] = (_Float16)(a[r] + b4[r]);
            }
        }
    }
    __syncthreads();

    // ---- stream V-frag image to global, coalesced dwordx4 ----
    const int nfrag = h ? 20 : 12;
    _Float16* vb = Vh2 + (size_t)b * (size_t)N_ * C_;
    for (int idx = tid; idx < nfrag*64; idx += 256) {
        const int fl = idx >> 6;
        const int el = idx & 63;
        const int vt = fl >> 1;
        const int g  = fl & 1;
        const int gf = ((n0 >> 5) + g)*16 + ctg0 + vt;
        *(uint4*)(vb + (size_t)gf*512 + el*8) = *(const uint4*)(s_s + fl*512 + el*8);
    }
}

// ---------------------------------------------------------------------------
// Kernel 2: flash attention v6b — PV on 16x16x32 via permuted-j (P straight
// from registers), exp2-fma softmax with fixed per-j-half max, j-split x2.
// launch_bounds(512,2): 256-reg cap -> NO SPILL (R7's (512,4) forced a 128
// unified-reg cap and spilled the K/V double buffers: 2 GB of scratch
// traffic per dispatch).
// ---------------------------------------------------------------------------
__global__ __launch_bounds__(512, 2) void flash_kernel(
    const _Float16* __restrict__ Qh, const _Float16* __restrict__ Kh,
    const _Float16* __restrict__ Vh2, const float* __restrict__ sem,
    const float* __restrict__ gma, float* __restrict__ out)
{
    __shared__ float s_o[4 * 32 * 64];   // 32 KB: [cw][reg 0..31][lane]
    __shared__ float s_mp[8*32];
    __shared__ float s_m2[4*32];
    __shared__ float s_l2[4*32];

    const int bid = blockIdx.x;          // 512 blocks
    const int b   = bid >> 7;
    const int i0  = (bid & 127) * 32;
    const int tid = threadIdx.x;
    const int w    = tid >> 6;           // 0..7
    const int lane = tid & 63;
    const int quad = lane >> 4;
    const int l15  = lane & 15;
    const int cw   = w & 3;
    const int jh   = w >> 2;
    const int cw4  = cw * 4;
    const int jbase = jh * 2048;
    const int jend  = jbase + 2048;

    // Q B-frags: B[k=d][n=i], d-chunk = quad
    const _Float16* qbase = Qh + (size_t)(b*4 + quad) * N_ * 8;
    const half8 qf0 = *(const half8*)(qbase + (size_t)(i0 + l15) * 8);
    const half8 qf1 = *(const half8*)(qbase + (size_t)(i0 + 16 + l15) * 8);
    const _Float16* klane = Kh + ((size_t)(b*4 + quad) * N_ + l15) * 8;
    const _Float16* vbase = Vh2 + (size_t)b * (size_t)N_ * C_ + lane*8;

    // ---- phase 0: exact row max, 8-way j-split ----
    float mx0 = -3e38f, mx1 = -3e38f;
    #pragma unroll 1
    for (int it = 0; it < 8; ++it) {
        const int jj = w*512 + it*64;
        #pragma unroll
        for (int js = 0; js < 4; ++js) {
            half8 kf = *(const half8*)(klane + (size_t)(jj + js*16) * 8);
            f32x4 z; z[0]=0.f; z[1]=0.f; z[2]=0.f; z[3]=0.f;
            f32x4 s0 = __builtin_amdgcn_mfma_f32_16x16x32_f16(kf, qf0, z, 0, 0, 0);
            f32x4 s1 = __builtin_amdgcn_mfma_f32_16x16x32_f16(kf, qf1, z, 0, 0, 0);
            #pragma unroll
            for (int r = 0; r < 4; ++r) { mx0 = fmaxf(mx0, s0[r]); mx1 = fmaxf(mx1, s1[r]); }
        }
    }
    mx0 = fmaxf(mx0, __shfl_xor(mx0, 16)); mx0 = fmaxf(mx0, __shfl_xor(mx0, 32));
    mx1 = fmaxf(mx1, __shfl_xor(mx1, 16)); mx1 = fmaxf(mx1, __shfl_xor(mx1, 32));
    if (lane < 32) s_mp[w*32 + lane] = (lane < 16) ? mx0 : mx1;
    __syncthreads();
    float mf0 = -3e38f, mf1 = -3e38f;
    #pragma unroll
    for (int ww = 0; ww < 4; ++ww) {        // combine the 4 chunks of MY j-half
        const int wi = jh*4 + ww;
        mf0 = fmaxf(mf0, s_mp[wi*32 + l15]);
        mf1 = fmaxf(mf1, s_mp[wi*32 + 16 + l15]);
    }
    const float mc0 = mf0 * L2E, mc1 = mf1 * L2E;

    // ---- main loop ----
    f32x4 acc[4][2];
    #pragma unroll
    for (int ct = 0; ct < 4; ++ct)
        #pragma unroll
        for (int f = 0; f < 2; ++f) { acc[ct][f][0]=0.f; acc[ct][f][1]=0.f; acc[ct][f][2]=0.f; acc[ct][f][3]=0.f; }
    float l0 = 0.f, l1 = 0.f;

    half8 ka[4], kb[4], va[2][4], vb[2][4];

    auto pref = [&](half8 (&kf)[4], half8 (&vf)[2][4], int j0) {
        #pragma unroll
        for (int js = 0; js < 4; ++js)
            kf[js] = *(const half8*)(klane + (size_t)(j0 + js*16) * 8);
        const int jc0 = j0 >> 5;
        #pragma unroll
        for (int g = 0; g < 2; ++g)
            #pragma unroll
            for (int ct = 0; ct < 4; ++ct)
                vf[g][ct] = *(const half8*)(vbase + (size_t)((jc0 + g)*16 + cw4 + ct) * 512);
    };

    auto step = [&](const half8 (&kf)[4], const half8 (&vf)[2][4],
                    half8 (&kfn)[4], half8 (&vfn)[2][4], int jnext) {
        f32x4 z; z[0]=0.f; z[1]=0.f; z[2]=0.f; z[3]=0.f;
        f32x4 sf0[4], sf1[4];
        #pragma unroll
        for (int js = 0; js < 4; ++js) {
            sf0[js] = __builtin_amdgcn_mfma_f32_16x16x32_f16(kf[js], qf0, z, 0, 0, 0);
            sf1[js] = __builtin_amdgcn_mfma_f32_16x16x32_f16(kf[js], qf1, z, 0, 0, 0);
        }
        if (jnext < jend) pref(kfn, vfn, jnext);

        #pragma unroll
        for (int g = 0; g < 2; ++g) {
            PBU p0, p1;
            #pragma unroll
            for (int tt = 0; tt < 2; ++tt) {
                const int js = 2*g + tt;
                float a0 = exp2f(fmaf(sf0[js][0], L2E, -mc0));
                float a1 = exp2f(fmaf(sf0[js][1], L2E, -mc0));
                float a2 = exp2f(fmaf(sf0[js][2], L2E, -mc0));
                float a3 = exp2f(fmaf(sf0[js][3], L2E, -mc0));
                l0 += (a0+a1)+(a2+a3);
                p0.h2[tt*2+0] = pk2(a0, a1); p0.h2[tt*2+1] = pk2(a2, a3);
                float b0 = exp2f(fmaf(sf1[js][0], L2E, -mc1));
                float b1 = exp2f(fmaf(sf1[js][1], L2E, -mc1));
                float b2 = exp2f(fmaf(sf1[js][2], L2E, -mc1));
                float b3 = exp2f(fmaf(sf1[js][3], L2E, -mc1));
                l1 += (b0+b1)+(b2+b3);
                p1.h2[tt*2+0] = pk2(b0, b1); p1.h2[tt*2+1] = pk2(b2, b3);
            }
            #pragma unroll
            for (int ct = 0; ct < 4; ++ct) {
                acc[ct][0] = __builtin_amdgcn_mfma_f32_16x16x32_f16(vf[g][ct], p0.h8, acc[ct][0], 0, 0, 0);
                acc[ct][1] = __builtin_amdgcn_mfma_f32_16x16x32_f16(vf[g][ct], p1.h8, acc[ct][1], 0, 0, 0);
            }
        }
    };

    pref(ka, va, jbase);
    #pragma unroll 1
    for (int s = 0; s < 16; ++s) {
        const int j0 = jbase + s*128;
        step(ka, va, kb, vb, j0 + 64);
        step(kb, vb, ka, va, j0 + 128);
    }

    // ---- l across quads (disjoint j per quad) ----
    l0 += __shfl_xor(l0, 16); l0 += __shfl_xor(l0, 32);
    l1 += __shfl_xor(l1, 16); l1 += __shfl_xor(l1, 32);

    // ---- merge j-halves through LDS, fused epilogue ----
    __syncthreads();
    if (jh == 1) {
        #pragma unroll
        for (int ct = 0; ct < 4; ++ct)
            #pragma unroll
            for (int e = 0; e < 4; ++e) {
                s_o[(cw*32 + ct*8 + e)*64 + lane]     = acc[ct][0][e];
                s_o[(cw*32 + ct*8 + 4 + e)*64 + lane] = acc[ct][1][e];
            }
        if (quad == 0) {
            s_m2[cw*32 + l15]      = mf0;  s_m2[cw*32 + 16 + l15] = mf1;
            s_l2[cw*32 + l15]      = l0;   s_l2[cw*32 + 16 + l15] = l1;
        }
    }
    __syncthreads();
    if (jh == 0) {
        const float md0 = s_m2[cw*32 + l15],      md1 = s_m2[cw*32 + 16 + l15];
        const float ld0 = s_l2[cw*32 + l15],      ld1 = s_l2[cw*32 + 16 + l15];
        const float g   = gma[0];
        const float mm0 = fmaxf(mf0, md0), mm1 = fmaxf(mf1, md1);
        const float as0 = exp2f((mf0 - mm0)*L2E), ad0 = exp2f((md0 - mm0)*L2E);
        const float as1 = exp2f((mf1 - mm1)*L2E), ad1 = exp2f((md1 - mm1)*L2E);
        const float ln0 = l0*as0 + ld0*ad0, ln1 = l1*as1 + ld1*ad1;
        const float ca0 = as0*g/ln0, cd0 = ad0*g/ln0;
        const float ca1 = as1*g/ln1, cd1 = ad1*g/ln1;
        #pragma unroll
        for (int ct = 0; ct < 4; ++ct)
            #pragma unroll
            for (int e = 0; e < 4; ++e) {
                const float od0 = s_o[(cw*32 + ct*8 + e)*64 + lane];
                const float od1 = s_o[(cw*32 + ct*8 + 4 + e)*64 + lane];
                const int c = cw*64 + ct*16 + quad*4 + e;
                const size_t idx0 = ((size_t)(b*C_ + c)) * N_ + i0 + l15;
                out[idx0]      = acc[ct][0][e]*ca0 + od0*cd0 + sem[idx0];
                out[idx0 + 16] = acc[ct][1][e]*ca1 + od1*cd1 + sem[idx0 + 16];
            }
    }
}

extern "C" void kernel_launch(void* const* d_in, const int* in_sizes, int n_in,
                              void* d_out, int out_size, void* d_ws, size_t ws_size,
                              hipStream_t stream) {
    const float* sem = (const float*)d_in[0];
    const float* str = (const float*)d_in[1];
    const float* Wq  = (const float*)d_in[2];
    const float* bq  = (const float*)d_in[3];
    const float* Wk  = (const float*)d_in[4];
    const float* bk  = (const float*)d_in[5];
    const float* Wv  = (const float*)d_in[6];
    const float* bv  = (const float*)d_in[7];
    const float* gma = (const float*)d_in[8];
    float* out = (float*)d_out;

    // Workspace (f16): Qh 1MB | Kh 1MB | Vh2 8MB | Wh 160KB
    _Float16* Qh  = (_Float16*)d_ws;
    _Float16* Kh  = Qh + (size_t)B_*N_*D_;
    _Float16* Vh2 = Kh + (size_t)B_*N_*D_;
    _Float16* Wh  = Vh2 + (size_t)B_*C_*N_;

    hipLaunchKernelGGL(wcvt_kernel, dim3(320), dim3(256), 0, stream, Wq, Wk, Wv, Wh);
    hipLaunchKernelGGL(proj_kernel, dim3(B_*(N_/64)*2), dim3(256), 0, stream,
                       sem, str, Wh, bq, bk, bv, Qh, Kh, Vh2);
    hipLaunchKernelGGL(flash_kernel, dim3(B_*(N_/32)), dim3(512), 0, stream,
                       Qh, Kh, Vh2, sem, gma, out);
}